// Round 19
// baseline (210.331 us; speedup 1.0000x reference)
//
#include <hip/hip_runtime.h>
#include <math.h>

#define BB   8
#define CIN  512
#define NSP  2304
#define OCH  640   // 64(q)+64(k)+512(v)
#define LL   48

#define AS1 __attribute__((address_space(1)))
#define AS3 __attribute__((address_space(3)))

typedef __attribute__((ext_vector_type(8))) short bf16x8;
typedef __attribute__((ext_vector_type(8))) unsigned short u16x8;
typedef __attribute__((ext_vector_type(4))) float f32x4;

__device__ inline unsigned short f2bf(float f) {
  unsigned int u = __float_as_uint(f);
  unsigned int r = (u + 0x7fffu + ((u >> 16) & 1u)) >> 16;   // RNE
  return (unsigned short)r;
}
__device__ inline float bf2f(unsigned short h) {
  return __uint_as_float(((unsigned int)h) << 16);
}

// ---------------------------------------------------------------------------
// T2 swizzle (rule #21): linear LDS dest + inverse-swizzled global SOURCE +
// swizzled READ. LDS[row][slot16B] = G[row][slot ^ (row&7)].

#define STAGE128x64(GP, LD, LDSN)                                              \
  {                                                                            \
    const unsigned short* gsrc_ = (GP);                                        \
    _Pragma("unroll") for (int cc_ = 0; cc_ < 4; cc_++) {                      \
      int base_ = w * 2048 + cc_ * 512;                                        \
      int row_ = w * 32 + cc_ * 8 + rsub;                                      \
      __builtin_amdgcn_global_load_lds(                                        \
          (const AS1 void*)(gsrc_ + (size_t)row_ * (LD) + scolb),              \
          (AS3 void*)&(LDSN)[base_], 16, 0, 0);                                \
    }                                                                          \
  }

// fused stage: waves 0-3 stage A (128x64), waves 4-7 stage B (64x64)
#define STAGEF(GPA, LDA, LA, GPB, LDB, LB)                                     \
  {                                                                            \
    if (w < 4) {                                                               \
      const unsigned short* gsrc_ = (GPA);                                     \
      _Pragma("unroll") for (int cc_ = 0; cc_ < 4; cc_++) {                    \
        int base_ = w * 2048 + cc_ * 512;                                      \
        int row_ = w * 32 + cc_ * 8 + rsub;                                    \
        __builtin_amdgcn_global_load_lds(                                      \
            (const AS1 void*)(gsrc_ + (size_t)row_ * (LDA) + scolb),           \
            (AS3 void*)&(LA)[base_], 16, 0, 0);                                \
      }                                                                        \
    } else {                                                                   \
      const unsigned short* gsrc_ = (GPB);                                     \
      int w2_ = w - 4;                                                         \
      _Pragma("unroll") for (int cc_ = 0; cc_ < 2; cc_++) {                    \
        int base_ = w2_ * 1024 + cc_ * 512;                                    \
        int row_ = w2_ * 16 + cc_ * 8 + rsub;                                  \
        __builtin_amdgcn_global_load_lds(                                      \
            (const AS1 void*)(gsrc_ + (size_t)row_ * (LDB) + scolb),           \
            (AS3 void*)&(LB)[base_], 16, 0, 0);                                \
      }                                                                        \
    }                                                                          \
  }

// one K=64 step, 4-wave (2x2), 64x64 per wave; acc[4][4]
#define MFMA_STEP(APTR, BPTR)                                                  \
  _Pragma("unroll") for (int kk_ = 0; kk_ < 2; kk_++) {                        \
    bf16x8 af_[4], bf_[4];                                                     \
    int kcol_ = (((kk_ * 4 + (lane >> 4)) ^ (lane & 7)) * 8);                  \
    _Pragma("unroll") for (int m_ = 0; m_ < 4; m_++)                           \
      af_[m_] = *(const bf16x8*)&(APTR)[(wr * 64 + m_ * 16 + (lane & 15)) * 64 + kcol_]; \
    _Pragma("unroll") for (int n_ = 0; n_ < 4; n_++)                           \
      bf_[n_] = *(const bf16x8*)&(BPTR)[(wc * 64 + n_ * 16 + (lane & 15)) * 64 + kcol_]; \
    _Pragma("unroll") for (int m_ = 0; m_ < 4; m_++)                           \
      _Pragma("unroll") for (int n_ = 0; n_ < 4; n_++)                         \
        acc[m_][n_] = __builtin_amdgcn_mfma_f32_16x16x32_bf16(                 \
            af_[m_], bf_[n_], acc[m_][n_], 0, 0, 0);                           \
  }

// one K=64 step, 8-wave (2x4), 64x16 per wave; acc[4]
#define MFMA_STEPF(APTR, BPTR)                                                 \
  _Pragma("unroll") for (int kk_ = 0; kk_ < 2; kk_++) {                        \
    bf16x8 af_[4], bf_;                                                        \
    int kcol_ = (((kk_ * 4 + (lane >> 4)) ^ (lane & 7)) * 8);                  \
    _Pragma("unroll") for (int m_ = 0; m_ < 4; m_++)                           \
      af_[m_] = *(const bf16x8*)&(APTR)[(wr * 64 + m_ * 16 + (lane & 15)) * 64 + kcol_]; \
    bf_ = *(const bf16x8*)&(BPTR)[(wc * 16 + (lane & 15)) * 64 + kcol_];       \
    _Pragma("unroll") for (int m_ = 0; m_ < 4; m_++)                           \
      acc[m_] = __builtin_amdgcn_mfma_f32_16x16x32_bf16(                       \
          af_[m_], bf_, acc[m_], 0, 0, 0);                                     \
  }

#define MFMA_PROLOG()                                                          \
  const int tid = threadIdx.x;                                                 \
  const int lane = tid & 63;                                                   \
  const int w = tid >> 6;                                                      \
  const int wr = w >> 1, wc = w & 1;                                           \
  const int rsub = lane >> 3;                                                  \
  const int scolb = ((lane & 7) ^ rsub) * 8;                                   \
  f32x4 acc[4][4] = {};                                                        \
  (void)scolb; (void)rsub; (void)wr; (void)wc;

// ---------------------------------------------------------------------------
// merged prep (stack W bf16 + bias + Pcat) AND x transpose, one launch.
#define NPREP ((OCH * CIN + 128 * NSP) / 256)
__global__ __launch_bounds__(256) void prep_and_transpose(
    const float* __restrict__ Wq, const float* __restrict__ bq,
    const float* __restrict__ Wk, const float* __restrict__ bk,
    const float* __restrict__ Wv, const float* __restrict__ bv,
    const float* __restrict__ rel_rows, const float* __restrict__ rel_cols,
    unsigned short* __restrict__ Wstb, float* __restrict__ bst,
    unsigned short* __restrict__ Pcatb,
    const float* __restrict__ x, unsigned short* __restrict__ xTb) {
  if (blockIdx.x < NPREP) {
    int idx = blockIdx.x * 256 + threadIdx.x;
    if (idx < OCH * CIN) {
      int row = idx >> 9;
      float val;
      if (row < 64)       val = Wq[idx];
      else if (row < 128) val = Wk[idx - (64 << 9)];
      else                val = Wv[idx - (128 << 9)];
      Wstb[idx] = f2bf(val);
      if (idx < OCH) {
        float bval;
        if (idx < 64)       bval = bq[idx];
        else if (idx < 128) bval = bk[idx - 64];
        else                bval = bv[idx - 128];
        bst[idx] = bval;
      }
    } else {
      int p = idx - OCH * CIN;          // < 128*2304
      int dd = p / NSP;
      int n = p - dd * NSP;
      int xr = n / LL;
      int ic = n - xr * LL;
      int shift = ic - xr + (LL - 1);
      float val = (dd < 64) ? rel_rows[shift * 64 + dd]
                            : rel_cols[shift * 64 + (dd - 64)];
      Pcatb[p] = f2bf(val);
    }
    return;
  }
  __shared__ float t[64][65];
  int bx = blockIdx.x - NPREP;          // < 36*8*8
  const int n0 = (bx % 36) * 64;
  const int c0 = ((bx / 36) % 8) * 64;
  const int b = bx / 288;
  const int j = threadIdx.x & 63;
  const int g = threadIdx.x >> 6;
  const float* xp = x + (size_t)b * CIN * NSP;
#pragma unroll
  for (int i = 0; i < 16; i++) {
    int cl = g * 16 + i;
    t[cl][j] = xp[(size_t)(c0 + cl) * NSP + n0 + j];
  }
  __syncthreads();
  unsigned short* op = xTb + (size_t)b * NSP * CIN;
#pragma unroll
  for (int i = 0; i < 16; i++) {
    int nl = g * 16 + i;
    op[(size_t)(n0 + nl) * CIN + c0 + j] = f2bf(t[j][nl]);
  }
}

// ---------------------------------------------------------------------------
// proj (single-buffer, 33 KB -> 4 blocks/CU): y16 = bf16(W@xT+b); BN partials
__global__ __launch_bounds__(256) void proj_mfma(
    const unsigned short* __restrict__ Wstb, const float* __restrict__ bst,
    const unsigned short* __restrict__ xTb, unsigned short* __restrict__ y16,
    float* __restrict__ part1, float* __restrict__ part2) {
  __shared__ unsigned short As[8192];
  __shared__ unsigned short Bs[8192];
  int sw = ((blockIdx.x & 7) * 90) + (blockIdx.x >> 3);   // 720 wg
  const int rb = sw % 5;
  const int nb = (sw / 5) % 18;
  const int b = sw / 90;
  const int r0 = rb * 128;
  const int n0 = nb * 128;
  MFMA_PROLOG();
  const unsigned short* A = Wstb + (size_t)r0 * CIN;
  const unsigned short* B = xTb + (size_t)b * NSP * CIN + (size_t)n0 * CIN;

  for (int t = 0; t < 8; ++t) {
    STAGE128x64(A + t * 64, CIN, As);
    STAGE128x64(B + t * 64, CIN, Bs);
    asm volatile("s_waitcnt vmcnt(0)" ::: "memory");
    __builtin_amdgcn_sched_barrier(0);
    __builtin_amdgcn_s_barrier();
    __builtin_amdgcn_s_setprio(1);
    MFMA_STEP(As, Bs);
    __builtin_amdgcn_s_setprio(0);
    __builtin_amdgcn_sched_barrier(0);
    __builtin_amdgcn_s_barrier();
  }

  float* sp = (float*)&As[0];
#pragma unroll
  for (int m = 0; m < 4; m++) {
#pragma unroll
    for (int r = 0; r < 4; r++) {
      int rl = wr * 64 + m * 16 + (lane >> 4) * 4 + r;
      int row = r0 + rl;
      float bias = bst[row];
      float s1 = 0.f, s2 = 0.f;
#pragma unroll
      for (int n = 0; n < 4; n++) {
        float yv = acc[m][n][r] + bias;
        s1 += yv;
        s2 += yv * yv;
        y16[((size_t)b * OCH + row) * NSP + n0 + wc * 64 + n * 16 + (lane & 15)] = f2bf(yv);
      }
#pragma unroll
      for (int off = 1; off < 16; off <<= 1) {
        s1 += __shfl_xor(s1, off);
        s2 += __shfl_xor(s2, off);
      }
      if ((lane & 15) == 0) {
        sp[rl * 2 + wc] = s1;
        sp[256 + rl * 2 + wc] = s2;
      }
    }
  }
  __syncthreads();
  if (tid < 128) {
    size_t pbase = ((size_t)b * 18 + nb) * OCH + r0 + tid;
    part1[pbase] = sp[tid * 2] + sp[tid * 2 + 1];
    part2[pbase] = sp[256 + tid * 2] + sp[256 + tid * 2 + 1];
  }
}

// reduce 144 partials/channel -> chanA/chanB
__global__ __launch_bounds__(256) void bn_finalize(
    const float* __restrict__ part1, const float* __restrict__ part2,
    const float* __restrict__ qs_, const float* __restrict__ qb_,
    const float* __restrict__ ks_, const float* __restrict__ kb_,
    const float* __restrict__ vs_, const float* __restrict__ vb_,
    float* __restrict__ chanA, float* __restrict__ chanB) {
  const int ch = blockIdx.x;
  const int tid = threadIdx.x;
  float s1 = 0.f, s2 = 0.f;
  for (int t = tid; t < 144; t += 256) {
    s1 += part1[(size_t)t * OCH + ch];
    s2 += part2[(size_t)t * OCH + ch];
  }
  __shared__ float sb[8];
#pragma unroll
  for (int off = 32; off > 0; off >>= 1) {
    s1 += __shfl_down(s1, off);
    s2 += __shfl_down(s2, off);
  }
  int lane = tid & 63, wid = tid >> 6;
  if (lane == 0) { sb[wid] = s1; sb[4 + wid] = s2; }
  __syncthreads();
  if (tid == 0) {
    float ts  = sb[0] + sb[1] + sb[2] + sb[3];
    float ts2 = sb[4] + sb[5] + sb[6] + sb[7];
    const float inv = 1.f / (float)(BB * NSP);
    float mean = ts * inv;
    float var  = ts2 * inv - mean * mean;
    float scale, bias;
    if (ch < 64)       { scale = qs_[ch];       bias = qb_[ch]; }
    else if (ch < 128) { scale = ks_[ch - 64];  bias = kb_[ch - 64]; }
    else               { scale = vs_[ch - 128]; bias = vb_[ch - 128]; }
    float a = scale * rsqrtf(var + 1e-5f);
    chanA[ch] = a;
    chanB[ch] = bias - mean * a;
  }
}

// merged BN+relu in place over all y16 + q/k transpose (through LDS)
__global__ __launch_bounds__(256) void bn_post(
    unsigned short* __restrict__ y16, const float* __restrict__ chanA,
    const float* __restrict__ chanB, unsigned short* __restrict__ qTb,
    unsigned short* __restrict__ kTb) {
  __shared__ unsigned short qk[128][64];
  const int n0 = blockIdx.x * 64;   // 36
  const int b = blockIdx.y;
  const int tid = threadIdx.x;
#pragma unroll
  for (int k = 0; k < 20; k++) {
    int v = tid + k * 256;          // < 5120
    int ch = v >> 3;
    int n8 = (v & 7) * 8;
    size_t off = ((size_t)b * OCH + ch) * NSP + n0 + n8;
    float a = chanA[ch], bo = chanB[ch];
    ushort4 u0 = *(ushort4*)&y16[off];
    ushort4 u1 = *(ushort4*)&y16[off + 4];
    ushort4 o0, o1;
    o0.x = f2bf(fmaxf(0.f, a * bf2f(u0.x) + bo));
    o0.y = f2bf(fmaxf(0.f, a * bf2f(u0.y) + bo));
    o0.z = f2bf(fmaxf(0.f, a * bf2f(u0.z) + bo));
    o0.w = f2bf(fmaxf(0.f, a * bf2f(u0.w) + bo));
    o1.x = f2bf(fmaxf(0.f, a * bf2f(u1.x) + bo));
    o1.y = f2bf(fmaxf(0.f, a * bf2f(u1.y) + bo));
    o1.z = f2bf(fmaxf(0.f, a * bf2f(u1.z) + bo));
    o1.w = f2bf(fmaxf(0.f, a * bf2f(u1.w) + bo));
    *(ushort4*)&y16[off] = o0;
    *(ushort4*)&y16[off + 4] = o1;
    if (ch < 128) {
      *(ushort4*)&qk[ch][n8] = o0;
      *(ushort4*)&qk[ch][n8 + 4] = o1;
    }
  }
  __syncthreads();
#pragma unroll
  for (int it = 0; it < 4; it++) {
    int combo = (tid >> 6) + it * 4;   // 0..15
    int plane = combo >> 3;
    int dg = combo & 7;
    int nl = tid & 63;
    unsigned short tmp[8];
#pragma unroll
    for (int d = 0; d < 8; d++) tmp[d] = qk[plane * 64 + dg * 8 + d][nl];
    unsigned short* out = (plane == 0) ? qTb : kTb;
    *(u16x8*)&out[((size_t)b * NSP + n0 + nl) * 64 + dg * 8] = *(u16x8*)tmp;
  }
}

// Gqp[b*4+kc][d][e] = partial q·q^T over k-chunk; also qsp partial row sums
__global__ __launch_bounds__(256) void gq_mfma(
    const unsigned short* __restrict__ y16, float* __restrict__ Gqp,
    float* __restrict__ qsp) {
  __shared__ float wlds[4 * 4096];
  const int bx = blockIdx.x;          // 32
  const int b = bx >> 2, kc = bx & 3;
  const int tid = threadIdx.x;
  const int lane = tid & 63;
  const int w = tid >> 6;
  const unsigned short* q = y16 + (size_t)b * OCH * NSP;
  f32x4 acc[4][4] = {};
  for (int k0 = kc * 576 + w * 32; k0 < (kc + 1) * 576; k0 += 128) {
    bf16x8 fr[4];
#pragma unroll
    for (int f = 0; f < 4; f++) {
      int row = f * 16 + (lane & 15);
      fr[f] = *(const bf16x8*)&q[(size_t)row * NSP + k0 + (lane >> 4) * 8];
    }
#pragma unroll
    for (int fm = 0; fm < 4; fm++)
#pragma unroll
      for (int fn = 0; fn < 4; fn++)
        acc[fm][fn] = __builtin_amdgcn_mfma_f32_16x16x32_bf16(
            fr[fm], fr[fn], acc[fm][fn], 0, 0, 0);
  }
#pragma unroll
  for (int fm = 0; fm < 4; fm++)
#pragma unroll
    for (int fn = 0; fn < 4; fn++)
#pragma unroll
      for (int r = 0; r < 4; r++) {
        int d = fm * 16 + (lane >> 4) * 4 + r;
        int e = fn * 16 + (lane & 15);
        wlds[w * 4096 + d * 64 + e] = acc[fm][fn][r];
      }
  {
    float s = 0.f;
    const unsigned short* qrow = q + (size_t)(tid >> 2) * NSP + kc * 576 + (tid & 3) * 144;
    for (int i = 0; i < 144; i += 4) {
      ushort4 u = *(const ushort4*)&qrow[i];
      s += bf2f(u.x) + bf2f(u.y) + bf2f(u.z) + bf2f(u.w);
    }
    s += __shfl_down(s, 1);
    s += __shfl_down(s, 2);
    if ((tid & 3) == 0) qsp[bx * 64 + (tid >> 2)] = s;
  }
  __syncthreads();
  for (int t = tid; t < 4096; t += 256)
    Gqp[(size_t)bx * 4096 + t] =
        wlds[t] + wlds[4096 + t] + wlds[8192 + t] + wlds[12288 + t];
}

// ---------------------------------------------------------------------------
// energy+exp (direct-store): Pp = bf16(exp(qT·kT^T)) + partials
__global__ __launch_bounds__(256) void energy_mfma(
    const unsigned short* __restrict__ qTb, const unsigned short* __restrict__ kTb,
    unsigned short* __restrict__ Pp, float* __restrict__ Ppart) {
  __shared__ unsigned short As[8192];
  __shared__ unsigned short Bs[8192];
  int sw = ((blockIdx.x & 7) * 324) + (blockIdx.x >> 3);   // 2592 wg
  const int jb = sw % 18;
  const int ib = (sw / 18) % 18;
  const int b = sw / 324;
  const int i0 = ib * 128;
  const int j0 = jb * 128;
  MFMA_PROLOG();
  STAGE128x64(qTb + ((size_t)b * NSP + i0) * 64, 64, As);
  STAGE128x64(kTb + ((size_t)b * NSP + j0) * 64, 64, Bs);
  __syncthreads();
  MFMA_STEP(As, Bs);
  __syncthreads();
  float* sp = (float*)As;
  unsigned short* pp = Pp + (size_t)b * NSP * NSP;
#pragma unroll
  for (int m = 0; m < 4; m++) {
#pragma unroll
    for (int r = 0; r < 4; r++) {
      int rl = wr * 64 + m * 16 + (lane >> 4) * 4 + r;
      int i = i0 + rl;
      float s1 = 0.f;
#pragma unroll
      for (int n = 0; n < 4; n++) {
        int j = j0 + wc * 64 + n * 16 + (lane & 15);
        unsigned short h = f2bf(__expf(acc[m][n][r]));
        pp[(size_t)i * NSP + j] = h;
        s1 += bf2f(h);
      }
#pragma unroll
      for (int off = 1; off < 16; off <<= 1) s1 += __shfl_xor(s1, off);
      if ((lane & 15) == 0) sp[rl * 2 + wc] = s1;
    }
  }
  __syncthreads();
  if (tid < 128)
    Ppart[((size_t)b * 18 + jb) * NSP + i0 + tid] = sp[tid * 2] + sp[tid * 2 + 1];
}

// ---------------------------------------------------------------------------
// Upart (single-buffer, 33 KB -> 4 blocks/CU)
__global__ __launch_bounds__(256) void up_mfma(
    const unsigned short* __restrict__ y16, const unsigned short* __restrict__ Pcatb,
    float* __restrict__ Upart) {
  __shared__ unsigned short As[8192];
  __shared__ unsigned short Bs[8192];
  int sw = ((blockIdx.x & 7) * 24) + (blockIdx.x >> 3);   // 192 wg
  const int cb = sw % 4;
  const int kc = (sw / 4) % 6;
  const int b = sw / 24;
  const int c0 = cb * 128;
  MFMA_PROLOG();
  const unsigned short* A = y16 + ((size_t)b * OCH + 128 + c0) * NSP + kc * 384;
  const unsigned short* B = Pcatb + kc * 384;

  for (int t = 0; t < 6; ++t) {
    STAGE128x64(A + t * 64, NSP, As);
    STAGE128x64(B + t * 64, NSP, Bs);
    asm volatile("s_waitcnt vmcnt(0)" ::: "memory");
    __builtin_amdgcn_sched_barrier(0);
    __builtin_amdgcn_s_barrier();
    __builtin_amdgcn_s_setprio(1);
    MFMA_STEP(As, Bs);
    __builtin_amdgcn_s_setprio(0);
    __builtin_amdgcn_sched_barrier(0);
    __builtin_amdgcn_s_barrier();
  }

  float* up = Upart + ((size_t)kc * BB + b) * CIN * 128 + (size_t)c0 * 128;
#pragma unroll
  for (int m = 0; m < 4; m++)
#pragma unroll
    for (int r = 0; r < 4; r++) {
      int rl = wr * 64 + m * 16 + (lane >> 4) * 4 + r;
#pragma unroll
      for (int n = 0; n < 4; n++) {
        int col = wc * 64 + n * 16 + (lane & 15);
        up[(size_t)rl * 128 + col] = acc[m][n][r];
      }
    }
}

// merged: up_reduce + rel_stats + combine_u. one block per channel c.
__global__ __launch_bounds__(256) void rel_finalize(
    const float* __restrict__ Upart, const float* __restrict__ Gqp,
    const float* __restrict__ qsp,
    const float* __restrict__ bnr_s, const float* __restrict__ bnr_b,
    const float* __restrict__ bnc_s, const float* __restrict__ bnc_b,
    float* __restrict__ offc, unsigned short* __restrict__ Ucb) {
  const int c = blockIdx.x;        // 512
  const int tid = threadIdx.x;
  __shared__ float U[8][128];
  __shared__ float ghw[2];
  for (int t = tid; t < 1024; t += 256) {
    int b = t >> 7, dd = t & 127;
    float s = 0.f;
#pragma unroll
    for (int kc = 0; kc < 6; kc++)
      s += Upart[(((size_t)kc * BB + b) * CIN + c) * 128 + dd];
    U[b][dd] = s;
  }
  __syncthreads();
  if (tid < 64) {
    const int d = tid;
    float s1h = 0.f, s2h = 0.f, s1w = 0.f, s2w = 0.f;
    for (int b = 0; b < BB; b++) {
      float uh = U[b][d], uw = U[b][64 + d];
      float th = 0.f, tw = 0.f;
      float qsd = 0.f;
#pragma unroll
      for (int kc = 0; kc < 4; kc++) {
        const float* G = Gqp + ((size_t)(b * 4 + kc)) * 4096 + d * 64;
        for (int e = 0; e < 64; e++) {
          float g = G[e];
          th += g * U[b][e];
          tw += g * U[b][64 + e];
        }
        qsd += qsp[(b * 4 + kc) * 64 + d];
      }
      s1h += uh * qsd;
      s2h += uh * th;
      s1w += uw * qsd;
      s2w += uw * tw;
    }
#pragma unroll
    for (int off = 32; off > 0; off >>= 1) {
      s1h += __shfl_down(s1h, off);
      s2h += __shfl_down(s2h, off);
      s1w += __shfl_down(s1w, off);
      s2w += __shfl_down(s2w, off);
    }
    if (d == 0) {
      const float inv = 1.f / (float)(BB * NSP);
      float mh = s1h * inv, vh = s2h * inv - mh * mh;
      float mw = s1w * inv, vw = s2w * inv - mw * mw;
      float gch = bnr_s[c] * rsqrtf(vh + 1e-5f);
      float gcw = bnc_s[c] * rsqrtf(vw + 1e-5f);
      ghw[0] = gch;
      ghw[1] = gcw;
      offc[c] = (bnr_b[c] - mh * gch) + (bnc_b[c] - mw * gcw);
    }
  }
  __syncthreads();
  for (int t = tid; t < 512; t += 256) {
    int b = t >> 6, d = t & 63;
    Ucb[((size_t)b * CIN + c) * 64 + d] =
        f2bf(U[b][d] * ghw[0] + U[b][64 + d] * ghw[1]);
  }
}

// ---------------------------------------------------------------------------
// fused (128c x 64i per block, SINGLE-buffer ~25 KB LDS -> 4 blocks/CU =
// 32 waves/CU; per step: stage -> vmcnt(0) -> barrier -> MFMA -> barrier;
// T2; T5; in-kernel rZ):
// dst[c,i] = gamma*( rZ[i]*sum_j v[c,j]*Pp[i,j] + sum_d Ucb[c,d]*qT[i,d]
//                  + offc[c] ) + x[c,i]
__global__ __launch_bounds__(512) void attn_fused_gemm(
    const unsigned short* __restrict__ y16,   // v at channel offset 128
    const unsigned short* __restrict__ Pp,
    const float* __restrict__ Ppart,
    const unsigned short* __restrict__ Ucb,
    const unsigned short* __restrict__ qTb,
    const float* __restrict__ offc,
    const float* __restrict__ gammap,
    const float* __restrict__ x,
    float* __restrict__ dst) {
  __shared__ unsigned short As[8192];      // 128x64 (16 KB)
  __shared__ unsigned short Bs[4096];      // 64x64 (8 KB)
  __shared__ float rzl[64];
  int sw = ((blockIdx.x & 7) * 144) + (blockIdx.x >> 3);  // 1152 wg, 144/XCD
  const int b = sw / 144;
  const int rest = sw % 144;
  const int cb = rest % 4;
  const int ib = rest / 4;              // 0..35
  const int c0 = cb * 128;
  const int i0 = ib * 64;
  const int tid = threadIdx.x;
  const int lane = tid & 63;
  const int w = tid >> 6;               // 0..7
  const int wr = w >> 2, wc = w & 3;    // 2x4; per-wave 64 rows x 16 cols
  const int rsub = lane >> 3;
  const int scolb = ((lane & 7) ^ rsub) * 8;
  const int l15 = lane & 15, l4 = lane >> 4;
  f32x4 acc[4] = {};

  const unsigned short* A = y16 + ((size_t)b * OCH + 128 + c0) * NSP;
  const unsigned short* B = Pp + (size_t)b * NSP * NSP + (size_t)i0 * NSP;
  const unsigned short* A2 = Ucb + (size_t)b * CIN * 64 + (size_t)c0 * 64;
  const unsigned short* B2 = qTb + ((size_t)b * NSP + i0) * 64;

  // rZ first so its loads are consumed before staging begins
  if (tid < 64) {
    float s = 0.f;
#pragma unroll
    for (int jb = 0; jb < 18; jb++)
      s += Ppart[((size_t)b * 18 + jb) * NSP + i0 + tid];
    rzl[tid] = 1.f / s;
  }
  asm volatile("s_waitcnt lgkmcnt(0)" ::: "memory");
  __builtin_amdgcn_sched_barrier(0);

  // tiles 0..35 = main K (Pp), tile 36 = rank-64 rel tile
  for (int tt = 0; tt < 37; ++tt) {
    if (tt < 36) {
      STAGEF(A + tt * 64, NSP, As, B + tt * 64, NSP, Bs);
    } else {
      STAGEF(A2, 64, As, B2, 64, Bs);
    }
    asm volatile("s_waitcnt vmcnt(0)" ::: "memory");
    __builtin_amdgcn_sched_barrier(0);
    __builtin_amdgcn_s_barrier();
    if (tt == 36) {
      // softmax normalization applies only to the V*P' accumulation
      float rz = rzl[wc * 16 + l15];
#pragma unroll
      for (int m = 0; m < 4; m++)
#pragma unroll
        for (int r = 0; r < 4; r++) acc[m][r] *= rz;
    }
    __builtin_amdgcn_s_setprio(1);
    MFMA_STEPF(As, Bs);
    __builtin_amdgcn_s_setprio(0);
    __builtin_amdgcn_sched_barrier(0);
    __builtin_amdgcn_s_barrier();
  }

  const float gmm = gammap[0];
  const float* xp = x + (size_t)b * CIN * NSP;
  float* dp = dst + (size_t)b * CIN * NSP;
#pragma unroll
  for (int m = 0; m < 4; m++) {
#pragma unroll
    for (int r = 0; r < 4; r++) {
      int c = c0 + wr * 64 + m * 16 + l4 * 4 + r;
      float off = offc[c];
      int i = i0 + wc * 16 + l15;
      size_t o = (size_t)c * NSP + i;
      dp[o] = gmm * (acc[m][r] + off) + xp[o];
    }
  }
}

// ---------------------------------------------------------------------------
extern "C" void kernel_launch(void* const* d_in, const int* in_sizes, int n_in,
                              void* d_out, int out_size, void* d_ws, size_t ws_size,
                              hipStream_t stream) {
  const float* x        = (const float*)d_in[0];
  const float* Wq       = (const float*)d_in[1];
  const float* bq       = (const float*)d_in[2];
  const float* q_scale  = (const float*)d_in[3];
  const float* q_bias   = (const float*)d_in[4];
  const float* Wk       = (const float*)d_in[5];
  const float* bk       = (const float*)d_in[6];
  const float* k_scale  = (const float*)d_in[7];
  const float* k_bias   = (const float*)d_in[8];
  const float* Wv       = (const float*)d_in[9];
  const float* bv       = (const float*)d_in[10];
  const float* v_scale  = (const float*)d_in[11];
  const float* v_bias   = (const float*)d_in[12];
  const float* rel_rows = (const float*)d_in[13];
  const float* rel_cols = (const float*)d_in[14];
  const float* bnr_s    = (const float*)d_in[15];
  const float* bnr_b    = (const float*)d_in[16];
  const float* bnc_s    = (const float*)d_in[17];
  const float* bnc_b    = (const float*)d_in[18];
  const float* gamma    = (const float*)d_in[19];
  float* dst = (float*)d_out;

  float* ws = (float*)d_ws;
  size_t o = 0;
  unsigned short* Wstb = (unsigned short*)(ws + o); o += (size_t)OCH * CIN / 2;
  float* bst    = ws + o; o += 1024;
  float* chanA  = ws + o; o += 1024;
  float* chanB  = ws + o; o += 1024;
  unsigned short* Pcatb = (unsigned short*)(ws + o); o += (size_t)128 * NSP / 2;
  unsigned short* y16 = (unsigned short*)(ws + o); o += (size_t)BB * OCH * NSP / 2;
  unsigned short* xTb = (unsigned short*)(ws + o); o += (size_t)BB * NSP * CIN / 2;
  unsigned short* Pp  = (unsigned short*)(ws + o); o += (size_t)BB * NSP * NSP / 2;
  float* Ppart  = ws + o; o += (size_t)BB * 18 * NSP;
  float* Upart  = ws + o; o += (size_t)6 * BB * CIN * 128;
  float* Gqp    = ws + o; o += (size_t)32 * 4096;
  float* part1  = ws + o; o += (size_t)BB * 18 * OCH;
  float* part2  = ws + o; o += (size_t)BB * 18 * OCH;
  float* qsp    = ws + o; o += (size_t)32 * 64;
  float* offc   = ws + o; o += 1024;
  unsigned short* qTb = (unsigned short*)(ws + o); o += (size_t)BB * NSP * 64 / 2;
  unsigned short* kTb = (unsigned short*)(ws + o); o += (size_t)BB * NSP * 64 / 2;
  unsigned short* Ucb = (unsigned short*)(ws + o); o += (size_t)BB * CIN * 64 / 2;

  prep_and_transpose<<<NPREP + 36 * 8 * BB, 256, 0, stream>>>(
      Wq, bq, Wk, bk, Wv, bv, rel_rows, rel_cols, Wstb, bst, Pcatb, x, xTb);

  proj_mfma<<<720, 256, 0, stream>>>(Wstb, bst, xTb, y16, part1, part2);
  bn_finalize<<<OCH, 256, 0, stream>>>(part1, part2, q_scale, q_bias, k_scale,
                                       k_bias, v_scale, v_bias, chanA, chanB);
  bn_post<<<dim3(36, BB), 256, 0, stream>>>(y16, chanA, chanB, qTb, kTb);
  gq_mfma<<<32, 256, 0, stream>>>(y16, Gqp, qsp);

  energy_mfma<<<2592, 256, 0, stream>>>(qTb, kTb, Pp, Ppart);

  up_mfma<<<192, 256, 0, stream>>>(y16, Pcatb, Upart);
  rel_finalize<<<CIN, 256, 0, stream>>>(Upart, Gqp, qsp, bnr_s, bnr_b,
                                        bnc_s, bnc_b, offc, Ucb);

  attn_fused_gemm<<<1152, 512, 0, stream>>>(y16, Pp, Ppart, Ucb, qTb, offc,
                                            gamma, x, dst);
}

// Round 20
// 202.721 us; speedup vs baseline: 1.0375x; 1.0375x over previous
//
#include <hip/hip_runtime.h>
#include <math.h>

#define BB   8
#define CIN  512
#define NSP  2304
#define OCH  640   // 64(q)+64(k)+512(v)
#define LL   48

#define AS1 __attribute__((address_space(1)))
#define AS3 __attribute__((address_space(3)))

typedef __attribute__((ext_vector_type(8))) short bf16x8;
typedef __attribute__((ext_vector_type(8))) unsigned short u16x8;
typedef __attribute__((ext_vector_type(4))) float f32x4;

__device__ inline unsigned short f2bf(float f) {
  unsigned int u = __float_as_uint(f);
  unsigned int r = (u + 0x7fffu + ((u >> 16) & 1u)) >> 16;   // RNE
  return (unsigned short)r;
}
__device__ inline float bf2f(unsigned short h) {
  return __uint_as_float(((unsigned int)h) << 16);
}

// ---------------------------------------------------------------------------
// T2 swizzle (rule #21): linear LDS dest + inverse-swizzled global SOURCE +
// swizzled READ. LDS[row][slot16B] = G[row][slot ^ (row&7)].

#define STAGE128x64(GP, LD, LDSN)                                              \
  {                                                                            \
    const unsigned short* gsrc_ = (GP);                                        \
    _Pragma("unroll") for (int cc_ = 0; cc_ < 4; cc_++) {                      \
      int base_ = w * 2048 + cc_ * 512;                                        \
      int row_ = w * 32 + cc_ * 8 + rsub;                                      \
      __builtin_amdgcn_global_load_lds(                                        \
          (const AS1 void*)(gsrc_ + (size_t)row_ * (LD) + scolb),              \
          (AS3 void*)&(LDSN)[base_], 16, 0, 0);                                \
    }                                                                          \
  }

// fused stage: waves 0-3 stage A (128x64), waves 4-7 stage B (64x64)
#define STAGEF(GPA, LDA, LA, GPB, LDB, LB)                                     \
  {                                                                            \
    if (w < 4) {                                                               \
      const unsigned short* gsrc_ = (GPA);                                     \
      _Pragma("unroll") for (int cc_ = 0; cc_ < 4; cc_++) {                    \
        int base_ = w * 2048 + cc_ * 512;                                      \
        int row_ = w * 32 + cc_ * 8 + rsub;                                    \
        __builtin_amdgcn_global_load_lds(                                      \
            (const AS1 void*)(gsrc_ + (size_t)row_ * (LDA) + scolb),           \
            (AS3 void*)&(LA)[base_], 16, 0, 0);                                \
      }                                                                        \
    } else {                                                                   \
      const unsigned short* gsrc_ = (GPB);                                     \
      int w2_ = w - 4;                                                         \
      _Pragma("unroll") for (int cc_ = 0; cc_ < 2; cc_++) {                    \
        int base_ = w2_ * 1024 + cc_ * 512;                                    \
        int row_ = w2_ * 16 + cc_ * 8 + rsub;                                  \
        __builtin_amdgcn_global_load_lds(                                      \
            (const AS1 void*)(gsrc_ + (size_t)row_ * (LDB) + scolb),           \
            (AS3 void*)&(LB)[base_], 16, 0, 0);                                \
      }                                                                        \
    }                                                                          \
  }

// one K=64 step, 4-wave (2x2), 64x64 per wave; acc[4][4]
#define MFMA_STEP(APTR, BPTR)                                                  \
  _Pragma("unroll") for (int kk_ = 0; kk_ < 2; kk_++) {                        \
    bf16x8 af_[4], bf_[4];                                                     \
    int kcol_ = (((kk_ * 4 + (lane >> 4)) ^ (lane & 7)) * 8);                  \
    _Pragma("unroll") for (int m_ = 0; m_ < 4; m_++)                           \
      af_[m_] = *(const bf16x8*)&(APTR)[(wr * 64 + m_ * 16 + (lane & 15)) * 64 + kcol_]; \
    _Pragma("unroll") for (int n_ = 0; n_ < 4; n_++)                           \
      bf_[n_] = *(const bf16x8*)&(BPTR)[(wc * 64 + n_ * 16 + (lane & 15)) * 64 + kcol_]; \
    _Pragma("unroll") for (int m_ = 0; m_ < 4; m_++)                           \
      _Pragma("unroll") for (int n_ = 0; n_ < 4; n_++)                         \
        acc[m_][n_] = __builtin_amdgcn_mfma_f32_16x16x32_bf16(                 \
            af_[m_], bf_[n_], acc[m_][n_], 0, 0, 0);                           \
  }

// one K=64 step, 8-wave (2x4), 64x16 per wave; acc[4]
#define MFMA_STEPF(APTR, BPTR)                                                 \
  _Pragma("unroll") for (int kk_ = 0; kk_ < 2; kk_++) {                        \
    bf16x8 af_[4], bf_;                                                        \
    int kcol_ = (((kk_ * 4 + (lane >> 4)) ^ (lane & 7)) * 8);                  \
    _Pragma("unroll") for (int m_ = 0; m_ < 4; m_++)                           \
      af_[m_] = *(const bf16x8*)&(APTR)[(wr * 64 + m_ * 16 + (lane & 15)) * 64 + kcol_]; \
    bf_ = *(const bf16x8*)&(BPTR)[(wc * 16 + (lane & 15)) * 64 + kcol_];       \
    _Pragma("unroll") for (int m_ = 0; m_ < 4; m_++)                           \
      acc[m_] = __builtin_amdgcn_mfma_f32_16x16x32_bf16(                       \
          af_[m_], bf_, acc[m_], 0, 0, 0);                                     \
  }

#define MFMA_PROLOG()                                                          \
  const int tid = threadIdx.x;                                                 \
  const int lane = tid & 63;                                                   \
  const int w = tid >> 6;                                                      \
  const int wr = w >> 1, wc = w & 1;                                           \
  const int rsub = lane >> 3;                                                  \
  const int scolb = ((lane & 7) ^ rsub) * 8;                                   \
  f32x4 acc[4][4] = {};                                                        \
  (void)scolb; (void)rsub; (void)wr; (void)wc;

// ---------------------------------------------------------------------------
// merged prep (stack W bf16 + bias + Pcat) AND x transpose, one launch.
#define NPREP ((OCH * CIN + 128 * NSP) / 256)
__global__ __launch_bounds__(256) void prep_and_transpose(
    const float* __restrict__ Wq, const float* __restrict__ bq,
    const float* __restrict__ Wk, const float* __restrict__ bk,
    const float* __restrict__ Wv, const float* __restrict__ bv,
    const float* __restrict__ rel_rows, const float* __restrict__ rel_cols,
    unsigned short* __restrict__ Wstb, float* __restrict__ bst,
    unsigned short* __restrict__ Pcatb,
    const float* __restrict__ x, unsigned short* __restrict__ xTb) {
  if (blockIdx.x < NPREP) {
    int idx = blockIdx.x * 256 + threadIdx.x;
    if (idx < OCH * CIN) {
      int row = idx >> 9;
      float val;
      if (row < 64)       val = Wq[idx];
      else if (row < 128) val = Wk[idx - (64 << 9)];
      else                val = Wv[idx - (128 << 9)];
      Wstb[idx] = f2bf(val);
      if (idx < OCH) {
        float bval;
        if (idx < 64)       bval = bq[idx];
        else if (idx < 128) bval = bk[idx - 64];
        else                bval = bv[idx - 128];
        bst[idx] = bval;
      }
    } else {
      int p = idx - OCH * CIN;          // < 128*2304
      int dd = p / NSP;
      int n = p - dd * NSP;
      int xr = n / LL;
      int ic = n - xr * LL;
      int shift = ic - xr + (LL - 1);
      float val = (dd < 64) ? rel_rows[shift * 64 + dd]
                            : rel_cols[shift * 64 + (dd - 64)];
      Pcatb[p] = f2bf(val);
    }
    return;
  }
  __shared__ float t[64][65];
  int bx = blockIdx.x - NPREP;          // < 36*8*8
  const int n0 = (bx % 36) * 64;
  const int c0 = ((bx / 36) % 8) * 64;
  const int b = bx / 288;
  const int j = threadIdx.x & 63;
  const int g = threadIdx.x >> 6;
  const float* xp = x + (size_t)b * CIN * NSP;
#pragma unroll
  for (int i = 0; i < 16; i++) {
    int cl = g * 16 + i;
    t[cl][j] = xp[(size_t)(c0 + cl) * NSP + n0 + j];
  }
  __syncthreads();
  unsigned short* op = xTb + (size_t)b * NSP * CIN;
#pragma unroll
  for (int i = 0; i < 16; i++) {
    int nl = g * 16 + i;
    op[(size_t)(n0 + nl) * CIN + c0 + j] = f2bf(t[j][nl]);
  }
}

// ---------------------------------------------------------------------------
// proj (single-buffer, 33 KB -> 4 blocks/CU): y16 = bf16(W@xT+b); BN partials
__global__ __launch_bounds__(256) void proj_mfma(
    const unsigned short* __restrict__ Wstb, const float* __restrict__ bst,
    const unsigned short* __restrict__ xTb, unsigned short* __restrict__ y16,
    float* __restrict__ part1, float* __restrict__ part2) {
  __shared__ unsigned short As[8192];
  __shared__ unsigned short Bs[8192];
  int sw = ((blockIdx.x & 7) * 90) + (blockIdx.x >> 3);   // 720 wg
  const int rb = sw % 5;
  const int nb = (sw / 5) % 18;
  const int b = sw / 90;
  const int r0 = rb * 128;
  const int n0 = nb * 128;
  MFMA_PROLOG();
  const unsigned short* A = Wstb + (size_t)r0 * CIN;
  const unsigned short* B = xTb + (size_t)b * NSP * CIN + (size_t)n0 * CIN;

  for (int t = 0; t < 8; ++t) {
    STAGE128x64(A + t * 64, CIN, As);
    STAGE128x64(B + t * 64, CIN, Bs);
    asm volatile("s_waitcnt vmcnt(0)" ::: "memory");
    __builtin_amdgcn_sched_barrier(0);
    __builtin_amdgcn_s_barrier();
    __builtin_amdgcn_s_setprio(1);
    MFMA_STEP(As, Bs);
    __builtin_amdgcn_s_setprio(0);
    __builtin_amdgcn_sched_barrier(0);
    __builtin_amdgcn_s_barrier();
  }

  float* sp = (float*)&As[0];
#pragma unroll
  for (int m = 0; m < 4; m++) {
#pragma unroll
    for (int r = 0; r < 4; r++) {
      int rl = wr * 64 + m * 16 + (lane >> 4) * 4 + r;
      int row = r0 + rl;
      float bias = bst[row];
      float s1 = 0.f, s2 = 0.f;
#pragma unroll
      for (int n = 0; n < 4; n++) {
        float yv = acc[m][n][r] + bias;
        s1 += yv;
        s2 += yv * yv;
        y16[((size_t)b * OCH + row) * NSP + n0 + wc * 64 + n * 16 + (lane & 15)] = f2bf(yv);
      }
#pragma unroll
      for (int off = 1; off < 16; off <<= 1) {
        s1 += __shfl_xor(s1, off);
        s2 += __shfl_xor(s2, off);
      }
      if ((lane & 15) == 0) {
        sp[rl * 2 + wc] = s1;
        sp[256 + rl * 2 + wc] = s2;
      }
    }
  }
  __syncthreads();
  if (tid < 128) {
    size_t pbase = ((size_t)b * 18 + nb) * OCH + r0 + tid;
    part1[pbase] = sp[tid * 2] + sp[tid * 2 + 1];
    part2[pbase] = sp[256 + tid * 2] + sp[256 + tid * 2 + 1];
  }
}

// reduce 144 partials/channel -> chanA/chanB
__global__ __launch_bounds__(256) void bn_finalize(
    const float* __restrict__ part1, const float* __restrict__ part2,
    const float* __restrict__ qs_, const float* __restrict__ qb_,
    const float* __restrict__ ks_, const float* __restrict__ kb_,
    const float* __restrict__ vs_, const float* __restrict__ vb_,
    float* __restrict__ chanA, float* __restrict__ chanB) {
  const int ch = blockIdx.x;
  const int tid = threadIdx.x;
  float s1 = 0.f, s2 = 0.f;
  for (int t = tid; t < 144; t += 256) {
    s1 += part1[(size_t)t * OCH + ch];
    s2 += part2[(size_t)t * OCH + ch];
  }
  __shared__ float sb[8];
#pragma unroll
  for (int off = 32; off > 0; off >>= 1) {
    s1 += __shfl_down(s1, off);
    s2 += __shfl_down(s2, off);
  }
  int lane = tid & 63, wid = tid >> 6;
  if (lane == 0) { sb[wid] = s1; sb[4 + wid] = s2; }
  __syncthreads();
  if (tid == 0) {
    float ts  = sb[0] + sb[1] + sb[2] + sb[3];
    float ts2 = sb[4] + sb[5] + sb[6] + sb[7];
    const float inv = 1.f / (float)(BB * NSP);
    float mean = ts * inv;
    float var  = ts2 * inv - mean * mean;
    float scale, bias;
    if (ch < 64)       { scale = qs_[ch];       bias = qb_[ch]; }
    else if (ch < 128) { scale = ks_[ch - 64];  bias = kb_[ch - 64]; }
    else               { scale = vs_[ch - 128]; bias = vb_[ch - 128]; }
    float a = scale * rsqrtf(var + 1e-5f);
    chanA[ch] = a;
    chanB[ch] = bias - mean * a;
  }
}

// merged BN+relu in place over all y16 + q/k transpose (through LDS)
__global__ __launch_bounds__(256) void bn_post(
    unsigned short* __restrict__ y16, const float* __restrict__ chanA,
    const float* __restrict__ chanB, unsigned short* __restrict__ qTb,
    unsigned short* __restrict__ kTb) {
  __shared__ unsigned short qk[128][64];
  const int n0 = blockIdx.x * 64;   // 36
  const int b = blockIdx.y;
  const int tid = threadIdx.x;
#pragma unroll
  for (int k = 0; k < 20; k++) {
    int v = tid + k * 256;          // < 5120
    int ch = v >> 3;
    int n8 = (v & 7) * 8;
    size_t off = ((size_t)b * OCH + ch) * NSP + n0 + n8;
    float a = chanA[ch], bo = chanB[ch];
    ushort4 u0 = *(ushort4*)&y16[off];
    ushort4 u1 = *(ushort4*)&y16[off + 4];
    ushort4 o0, o1;
    o0.x = f2bf(fmaxf(0.f, a * bf2f(u0.x) + bo));
    o0.y = f2bf(fmaxf(0.f, a * bf2f(u0.y) + bo));
    o0.z = f2bf(fmaxf(0.f, a * bf2f(u0.z) + bo));
    o0.w = f2bf(fmaxf(0.f, a * bf2f(u0.w) + bo));
    o1.x = f2bf(fmaxf(0.f, a * bf2f(u1.x) + bo));
    o1.y = f2bf(fmaxf(0.f, a * bf2f(u1.y) + bo));
    o1.z = f2bf(fmaxf(0.f, a * bf2f(u1.z) + bo));
    o1.w = f2bf(fmaxf(0.f, a * bf2f(u1.w) + bo));
    *(ushort4*)&y16[off] = o0;
    *(ushort4*)&y16[off + 4] = o1;
    if (ch < 128) {
      *(ushort4*)&qk[ch][n8] = o0;
      *(ushort4*)&qk[ch][n8 + 4] = o1;
    }
  }
  __syncthreads();
#pragma unroll
  for (int it = 0; it < 4; it++) {
    int combo = (tid >> 6) + it * 4;   // 0..15
    int plane = combo >> 3;
    int dg = combo & 7;
    int nl = tid & 63;
    unsigned short tmp[8];
#pragma unroll
    for (int d = 0; d < 8; d++) tmp[d] = qk[plane * 64 + dg * 8 + d][nl];
    unsigned short* out = (plane == 0) ? qTb : kTb;
    *(u16x8*)&out[((size_t)b * NSP + n0 + nl) * 64 + dg * 8] = *(u16x8*)tmp;
  }
}

// Gqp[b*4+kc][d][e] = partial q·q^T over k-chunk; also qsp partial row sums
__global__ __launch_bounds__(256) void gq_mfma(
    const unsigned short* __restrict__ y16, float* __restrict__ Gqp,
    float* __restrict__ qsp) {
  __shared__ float wlds[4 * 4096];
  const int bx = blockIdx.x;          // 32
  const int b = bx >> 2, kc = bx & 3;
  const int tid = threadIdx.x;
  const int lane = tid & 63;
  const int w = tid >> 6;
  const unsigned short* q = y16 + (size_t)b * OCH * NSP;
  f32x4 acc[4][4] = {};
  for (int k0 = kc * 576 + w * 32; k0 < (kc + 1) * 576; k0 += 128) {
    bf16x8 fr[4];
#pragma unroll
    for (int f = 0; f < 4; f++) {
      int row = f * 16 + (lane & 15);
      fr[f] = *(const bf16x8*)&q[(size_t)row * NSP + k0 + (lane >> 4) * 8];
    }
#pragma unroll
    for (int fm = 0; fm < 4; fm++)
#pragma unroll
      for (int fn = 0; fn < 4; fn++)
        acc[fm][fn] = __builtin_amdgcn_mfma_f32_16x16x32_bf16(
            fr[fm], fr[fn], acc[fm][fn], 0, 0, 0);
  }
#pragma unroll
  for (int fm = 0; fm < 4; fm++)
#pragma unroll
    for (int fn = 0; fn < 4; fn++)
#pragma unroll
      for (int r = 0; r < 4; r++) {
        int d = fm * 16 + (lane >> 4) * 4 + r;
        int e = fn * 16 + (lane & 15);
        wlds[w * 4096 + d * 64 + e] = acc[fm][fn][r];
      }
  {
    float s = 0.f;
    const unsigned short* qrow = q + (size_t)(tid >> 2) * NSP + kc * 576 + (tid & 3) * 144;
    for (int i = 0; i < 144; i += 4) {
      ushort4 u = *(const ushort4*)&qrow[i];
      s += bf2f(u.x) + bf2f(u.y) + bf2f(u.z) + bf2f(u.w);
    }
    s += __shfl_down(s, 1);
    s += __shfl_down(s, 2);
    if ((tid & 3) == 0) qsp[bx * 64 + (tid >> 2)] = s;
  }
  __syncthreads();
  for (int t = tid; t < 4096; t += 256)
    Gqp[(size_t)bx * 4096 + t] =
        wlds[t] + wlds[4096 + t] + wlds[8192 + t] + wlds[12288 + t];
}

// ---------------------------------------------------------------------------
// energy+exp (direct-store): Pp = bf16(exp(qT·kT^T)) + partials
__global__ __launch_bounds__(256) void energy_mfma(
    const unsigned short* __restrict__ qTb, const unsigned short* __restrict__ kTb,
    unsigned short* __restrict__ Pp, float* __restrict__ Ppart) {
  __shared__ unsigned short As[8192];
  __shared__ unsigned short Bs[8192];
  int sw = ((blockIdx.x & 7) * 324) + (blockIdx.x >> 3);   // 2592 wg
  const int jb = sw % 18;
  const int ib = (sw / 18) % 18;
  const int b = sw / 324;
  const int i0 = ib * 128;
  const int j0 = jb * 128;
  MFMA_PROLOG();
  STAGE128x64(qTb + ((size_t)b * NSP + i0) * 64, 64, As);
  STAGE128x64(kTb + ((size_t)b * NSP + j0) * 64, 64, Bs);
  __syncthreads();
  MFMA_STEP(As, Bs);
  __syncthreads();
  float* sp = (float*)As;
  unsigned short* pp = Pp + (size_t)b * NSP * NSP;
#pragma unroll
  for (int m = 0; m < 4; m++) {
#pragma unroll
    for (int r = 0; r < 4; r++) {
      int rl = wr * 64 + m * 16 + (lane >> 4) * 4 + r;
      int i = i0 + rl;
      float s1 = 0.f;
#pragma unroll
      for (int n = 0; n < 4; n++) {
        int j = j0 + wc * 64 + n * 16 + (lane & 15);
        unsigned short h = f2bf(__expf(acc[m][n][r]));
        pp[(size_t)i * NSP + j] = h;
        s1 += bf2f(h);
      }
#pragma unroll
      for (int off = 1; off < 16; off <<= 1) s1 += __shfl_xor(s1, off);
      if ((lane & 15) == 0) sp[rl * 2 + wc] = s1;
    }
  }
  __syncthreads();
  if (tid < 128)
    Ppart[((size_t)b * 18 + jb) * NSP + i0 + tid] = sp[tid * 2] + sp[tid * 2 + 1];
}

// ---------------------------------------------------------------------------
// Upart (single-buffer, 33 KB -> 4 blocks/CU)
__global__ __launch_bounds__(256) void up_mfma(
    const unsigned short* __restrict__ y16, const unsigned short* __restrict__ Pcatb,
    float* __restrict__ Upart) {
  __shared__ unsigned short As[8192];
  __shared__ unsigned short Bs[8192];
  int sw = ((blockIdx.x & 7) * 24) + (blockIdx.x >> 3);   // 192 wg
  const int cb = sw % 4;
  const int kc = (sw / 4) % 6;
  const int b = sw / 24;
  const int c0 = cb * 128;
  MFMA_PROLOG();
  const unsigned short* A = y16 + ((size_t)b * OCH + 128 + c0) * NSP + kc * 384;
  const unsigned short* B = Pcatb + kc * 384;

  for (int t = 0; t < 6; ++t) {
    STAGE128x64(A + t * 64, NSP, As);
    STAGE128x64(B + t * 64, NSP, Bs);
    asm volatile("s_waitcnt vmcnt(0)" ::: "memory");
    __builtin_amdgcn_sched_barrier(0);
    __builtin_amdgcn_s_barrier();
    __builtin_amdgcn_s_setprio(1);
    MFMA_STEP(As, Bs);
    __builtin_amdgcn_s_setprio(0);
    __builtin_amdgcn_sched_barrier(0);
    __builtin_amdgcn_s_barrier();
  }

  float* up = Upart + ((size_t)kc * BB + b) * CIN * 128 + (size_t)c0 * 128;
#pragma unroll
  for (int m = 0; m < 4; m++)
#pragma unroll
    for (int r = 0; r < 4; r++) {
      int rl = wr * 64 + m * 16 + (lane >> 4) * 4 + r;
#pragma unroll
      for (int n = 0; n < 4; n++) {
        int col = wc * 64 + n * 16 + (lane & 15);
        up[(size_t)rl * 128 + col] = acc[m][n][r];
      }
    }
}

// merged: up_reduce + rel_stats + combine_u. one block per channel c.
__global__ __launch_bounds__(256) void rel_finalize(
    const float* __restrict__ Upart, const float* __restrict__ Gqp,
    const float* __restrict__ qsp,
    const float* __restrict__ bnr_s, const float* __restrict__ bnr_b,
    const float* __restrict__ bnc_s, const float* __restrict__ bnc_b,
    float* __restrict__ offc, unsigned short* __restrict__ Ucb) {
  const int c = blockIdx.x;        // 512
  const int tid = threadIdx.x;
  __shared__ float U[8][128];
  __shared__ float ghw[2];
  for (int t = tid; t < 1024; t += 256) {
    int b = t >> 7, dd = t & 127;
    float s = 0.f;
#pragma unroll
    for (int kc = 0; kc < 6; kc++)
      s += Upart[(((size_t)kc * BB + b) * CIN + c) * 128 + dd];
    U[b][dd] = s;
  }
  __syncthreads();
  if (tid < 64) {
    const int d = tid;
    float s1h = 0.f, s2h = 0.f, s1w = 0.f, s2w = 0.f;
    for (int b = 0; b < BB; b++) {
      float uh = U[b][d], uw = U[b][64 + d];
      float th = 0.f, tw = 0.f;
      float qsd = 0.f;
#pragma unroll
      for (int kc = 0; kc < 4; kc++) {
        const float* G = Gqp + ((size_t)(b * 4 + kc)) * 4096 + d * 64;
        for (int e = 0; e < 64; e++) {
          float g = G[e];
          th += g * U[b][e];
          tw += g * U[b][64 + e];
        }
        qsd += qsp[(b * 4 + kc) * 64 + d];
      }
      s1h += uh * qsd;
      s2h += uh * th;
      s1w += uw * qsd;
      s2w += uw * tw;
    }
#pragma unroll
    for (int off = 32; off > 0; off >>= 1) {
      s1h += __shfl_down(s1h, off);
      s2h += __shfl_down(s2h, off);
      s1w += __shfl_down(s1w, off);
      s2w += __shfl_down(s2w, off);
    }
    if (d == 0) {
      const float inv = 1.f / (float)(BB * NSP);
      float mh = s1h * inv, vh = s2h * inv - mh * mh;
      float mw = s1w * inv, vw = s2w * inv - mw * mw;
      float gch = bnr_s[c] * rsqrtf(vh + 1e-5f);
      float gcw = bnc_s[c] * rsqrtf(vw + 1e-5f);
      ghw[0] = gch;
      ghw[1] = gcw;
      offc[c] = (bnr_b[c] - mh * gch) + (bnc_b[c] - mw * gcw);
    }
  }
  __syncthreads();
  for (int t = tid; t < 512; t += 256) {
    int b = t >> 6, d = t & 63;
    Ucb[((size_t)b * CIN + c) * 64 + d] =
        f2bf(U[b][d] * ghw[0] + U[b][64 + d] * ghw[1]);
  }
}

// ---------------------------------------------------------------------------
// fused (r16-proven: 128c x 64i per block, 512 thr, 8 waves 2x4 of 64x16;
// 48.5 KB LDS -> 3 blocks/CU; 2-phase stage-early, vmcnt(0), 1 barrier/step;
// T2; T5; in-kernel rZ):
// dst[c,i] = gamma*( rZ[i]*sum_j v[c,j]*Pp[i,j] + sum_d Ucb[c,d]*qT[i,d]
//                  + offc[c] ) + x[c,i]
__global__ __launch_bounds__(512) void attn_fused_gemm(
    const unsigned short* __restrict__ y16,   // v at channel offset 128
    const unsigned short* __restrict__ Pp,
    const float* __restrict__ Ppart,
    const unsigned short* __restrict__ Ucb,
    const unsigned short* __restrict__ qTb,
    const float* __restrict__ offc,
    const float* __restrict__ gammap,
    const float* __restrict__ x,
    float* __restrict__ dst) {
  __shared__ unsigned short As[2][8192];   // 128x64 dbuf (32 KB)
  __shared__ unsigned short Bs[2][4096];   // 64x64 dbuf (16 KB)
  __shared__ float rzl[64];
  int sw = ((blockIdx.x & 7) * 144) + (blockIdx.x >> 3);  // 1152 wg, 144/XCD
  const int b = sw / 144;
  const int rest = sw % 144;
  const int cb = rest % 4;
  const int ib = rest / 4;              // 0..35
  const int c0 = cb * 128;
  const int i0 = ib * 64;
  const int tid = threadIdx.x;
  const int lane = tid & 63;
  const int w = tid >> 6;               // 0..7
  const int wr = w >> 2, wc = w & 3;    // 2x4; per-wave 64 rows x 16 cols
  const int rsub = lane >> 3;
  const int scolb = ((lane & 7) ^ rsub) * 8;
  const int l15 = lane & 15, l4 = lane >> 4;
  f32x4 acc[4] = {};

  const unsigned short* A = y16 + ((size_t)b * OCH + 128 + c0) * NSP;
  const unsigned short* B = Pp + (size_t)b * NSP * NSP + (size_t)i0 * NSP;
  const unsigned short* A2 = Ucb + (size_t)b * CIN * 64 + (size_t)c0 * 64;
  const unsigned short* B2 = qTb + ((size_t)b * NSP + i0) * 64;

  // rZ first so its loads are consumed before staging begins
  if (tid < 64) {
    float s = 0.f;
#pragma unroll
    for (int jb = 0; jb < 18; jb++)
      s += Ppart[((size_t)b * 18 + jb) * NSP + i0 + tid];
    rzl[tid] = 1.f / s;
  }
  asm volatile("s_waitcnt lgkmcnt(0)" ::: "memory");
  __builtin_amdgcn_sched_barrier(0);

  // prologue: stage tile 0
  STAGEF(A, NSP, As[0], B, NSP, Bs[0]);
  asm volatile("s_waitcnt vmcnt(0)" ::: "memory");
  __builtin_amdgcn_sched_barrier(0);
  __builtin_amdgcn_s_barrier();

  int cur = 0;
  // tiles 0..35 = main K (Pp), tile 36 = rank-64 rel tile
  for (int tt = 0; tt < 37; ++tt) {
    if (tt + 1 < 36) {
      STAGEF(A + (tt + 1) * 64, NSP, As[cur ^ 1], B + (tt + 1) * 64, NSP, Bs[cur ^ 1]);
    } else if (tt + 1 == 36) {
      STAGEF(A2, 64, As[cur ^ 1], B2, 64, Bs[cur ^ 1]);
    }
    if (tt == 36) {
      // softmax normalization applies only to the V*P' accumulation
      float rz = rzl[wc * 16 + l15];
#pragma unroll
      for (int m = 0; m < 4; m++)
#pragma unroll
        for (int r = 0; r < 4; r++) acc[m][r] *= rz;
    }
    __builtin_amdgcn_s_setprio(1);
    MFMA_STEPF(As[cur], Bs[cur]);
    __builtin_amdgcn_s_setprio(0);
    asm volatile("s_waitcnt vmcnt(0)" ::: "memory");
    __builtin_amdgcn_sched_barrier(0);
    __builtin_amdgcn_s_barrier();
    cur ^= 1;
  }

  const float gmm = gammap[0];
  const float* xp = x + (size_t)b * CIN * NSP;
  float* dp = dst + (size_t)b * CIN * NSP;
#pragma unroll
  for (int m = 0; m < 4; m++) {
#pragma unroll
    for (int r = 0; r < 4; r++) {
      int c = c0 + wr * 64 + m * 16 + l4 * 4 + r;
      float off = offc[c];
      int i = i0 + wc * 16 + l15;
      size_t o = (size_t)c * NSP + i;
      dp[o] = gmm * (acc[m][r] + off) + xp[o];
    }
  }
}

// ---------------------------------------------------------------------------
extern "C" void kernel_launch(void* const* d_in, const int* in_sizes, int n_in,
                              void* d_out, int out_size, void* d_ws, size_t ws_size,
                              hipStream_t stream) {
  const float* x        = (const float*)d_in[0];
  const float* Wq       = (const float*)d_in[1];
  const float* bq       = (const float*)d_in[2];
  const float* q_scale  = (const float*)d_in[3];
  const float* q_bias   = (const float*)d_in[4];
  const float* Wk       = (const float*)d_in[5];
  const float* bk       = (const float*)d_in[6];
  const float* k_scale  = (const float*)d_in[7];
  const float* k_bias   = (const float*)d_in[8];
  const float* Wv       = (const float*)d_in[9];
  const float* bv       = (const float*)d_in[10];
  const float* v_scale  = (const float*)d_in[11];
  const float* v_bias   = (const float*)d_in[12];
  const float* rel_rows = (const float*)d_in[13];
  const float* rel_cols = (const float*)d_in[14];
  const float* bnr_s    = (const float*)d_in[15];
  const float* bnr_b    = (const float*)d_in[16];
  const float* bnc_s    = (const float*)d_in[17];
  const float* bnc_b    = (const float*)d_in[18];
  const float* gamma    = (const float*)d_in[19];
  float* dst = (float*)d_out;

  float* ws = (float*)d_ws;
  size_t o = 0;
  unsigned short* Wstb = (unsigned short*)(ws + o); o += (size_t)OCH * CIN / 2;
  float* bst    = ws + o; o += 1024;
  float* chanA  = ws + o; o += 1024;
  float* chanB  = ws + o; o += 1024;
  unsigned short* Pcatb = (unsigned short*)(ws + o); o += (size_t)128 * NSP / 2;
  unsigned short* y16 = (unsigned short*)(ws + o); o += (size_t)BB * OCH * NSP / 2;
  unsigned short* xTb = (unsigned short*)(ws + o); o += (size_t)BB * NSP * CIN / 2;
  unsigned short* Pp  = (unsigned short*)(ws + o); o += (size_t)BB * NSP * NSP / 2;
  float* Ppart  = ws + o; o += (size_t)BB * 18 * NSP;
  float* Upart  = ws + o; o += (size_t)6 * BB * CIN * 128;
  float* Gqp    = ws + o; o += (size_t)32 * 4096;
  float* part1  = ws + o; o += (size_t)BB * 18 * OCH;
  float* part2  = ws + o; o += (size_t)BB * 18 * OCH;
  float* qsp    = ws + o; o += (size_t)32 * 64;
  float* offc   = ws + o; o += 1024;
  unsigned short* qTb = (unsigned short*)(ws + o); o += (size_t)BB * NSP * 64 / 2;
  unsigned short* kTb = (unsigned short*)(ws + o); o += (size_t)BB * NSP * 64 / 2;
  unsigned short* Ucb = (unsigned short*)(ws + o); o += (size_t)BB * CIN * 64 / 2;

  prep_and_transpose<<<NPREP + 36 * 8 * BB, 256, 0, stream>>>(
      Wq, bq, Wk, bk, Wv, bv, rel_rows, rel_cols, Wstb, bst, Pcatb, x, xTb);

  proj_mfma<<<720, 256, 0, stream>>>(Wstb, bst, xTb, y16, part1, part2);
  bn_finalize<<<OCH, 256, 0, stream>>>(part1, part2, q_scale, q_bias, k_scale,
                                       k_bias, v_scale, v_bias, chanA, chanB);
  bn_post<<<dim3(36, BB), 256, 0, stream>>>(y16, chanA, chanB, qTb, kTb);
  gq_mfma<<<32, 256, 0, stream>>>(y16, Gqp, qsp);

  energy_mfma<<<2592, 256, 0, stream>>>(qTb, kTb, Pp, Ppart);

  up_mfma<<<192, 256, 0, stream>>>(y16, Pcatb, Upart);
  rel_finalize<<<CIN, 256, 0, stream>>>(Upart, Gqp, qsp, bnr_s, bnr_b,
                                        bnc_s, bnc_b, offc, Ucb);

  attn_fused_gemm<<<1152, 512, 0, stream>>>(y16, Pp, Ppart, Ucb, qTb, offc,
                                            gamma, x, dst);
}